// Round 4
// baseline (516.460 us; speedup 1.0000x reference)
//
#include <hip/hip_runtime.h>
#include <cstdint>
#include <cstddef>

#define NN 8192
#define HEADS 4

typedef __attribute__((ext_vector_type(4))) float  f4;
typedef __attribute__((ext_vector_type(4))) int    i4;
typedef __attribute__((ext_vector_type(8))) short  short8;
typedef __attribute__((ext_vector_type(4))) unsigned short us4;
typedef __attribute__((ext_vector_type(4))) unsigned int   u4;
typedef __attribute__((ext_vector_type(2))) unsigned int   u2;
typedef unsigned int uint32;

__device__ __forceinline__ unsigned short f2bf(float f) {
    unsigned int u = __builtin_bit_cast(unsigned int, f);
    u += 0x7FFFu + ((u >> 16) & 1u);           // RNE
    return (unsigned short)(u >> 16);
}

// ---------------- K0: x -> bf16 (row-major), W -> WT bf16 (transposed) ----
__global__ void k0_convert(const float* __restrict__ x, const float* __restrict__ W,
                           unsigned short* __restrict__ xb, unsigned short* __restrict__ WT) {
    int b = blockIdx.x;
    if (b < 2048) {
        int idx = (b * 256 + threadIdx.x) * 4;
        f4 v = *(const f4*)(x + idx);
        us4 o;
        o.x = f2bf(v.x); o.y = f2bf(v.y); o.z = f2bf(v.z); o.w = f2bf(v.w);
        *(us4*)(xb + idx) = o;
    } else {
        int f = b - 2048;               // 0..255 : input-feature row of W
        int c = threadIdx.x;            // 0..255 : (head*64+d) column
        WT[c * 256 + f] = f2bf(W[f * 256 + c]);
    }
}

// ---------------- Kpack: adj -> byte masks (0xFF / 0x00) in k2's fragment
// order: addr = ((itile*256 + jb)*2 + r)*512 + lane*8 + t
// where i = itile*32 + r*16 + (lane&15), j = jb*32 + (lane>>4)*8 + t.
__global__ __launch_bounds__(256) void kpack(const int* __restrict__ adj,
                                             unsigned char* __restrict__ adjF) {
    __shared__ uint32 tile[32 * 66];
    const int itile = blockIdx.x >> 5;      // 0..255
    const int jgrp  = blockIdx.x & 31;      // 0..31
    const int i0 = itile * 32;
    const int j0 = jgrp * 256;
    const int tid = threadIdx.x;
    const int rrow = tid >> 6;              // 0..3
    const int jc   = (tid & 63) * 4;        // 0..252

    #pragma unroll
    for (int it = 0; it < 8; ++it) {
        int row = it * 4 + rrow;
        i4 v = *(const i4*)(adj + (size_t)(i0 + row) * NN + j0 + jc);
        uint32 w = (v.x ? 0xFFu : 0u) | (v.y ? 0xFF00u : 0u) |
                   (v.z ? 0xFF0000u : 0u) | (v.w ? 0xFF000000u : 0u);
        tile[row * 66 + (jc >> 2)] = w;
    }
    __syncthreads();

    const size_t bbase = (size_t)(itile * 256 + jgrp * 8) * 1024;
    #pragma unroll
    for (int k = 0; k < 4; ++k) {
        int s    = k * 256 + tid;           // 0..1023
        int jbl  = s >> 7;
        int r    = (s >> 6) & 1;
        int lane = s & 63;
        int col  = lane & 15, quad = lane >> 4;
        int row  = r * 16 + col;
        int c    = jbl * 8 + quad * 2;
        uint32 w0 = tile[row * 66 + c];
        uint32 w1 = tile[row * 66 + c + 1];
        *(u2*)(adjF + bbase + (size_t)s * 8) = u2{w0, w1};
    }
}

// ---------------- K1: h = x*W (bf16 MFMA) -> hF (bf16 B-frag) + fp32 exp tables
__global__ __launch_bounds__(256) void k1_hgemm(
    const unsigned short* __restrict__ xb, const unsigned short* __restrict__ WT,
    const float* __restrict__ aS, const float* __restrict__ aD,
    unsigned short* __restrict__ hF,
    float* __restrict__ sE, float* __restrict__ sE2,
    float* __restrict__ dE, float* __restrict__ dE2)
{
    const int tid  = threadIdx.x;
    const int head = tid >> 6;
    const int lane = tid & 63;
    const int col  = lane & 15;
    const int quad = lane >> 4;
    const int i0   = blockIdx.x * 32;

    const unsigned short* ar0 = xb + (size_t)(i0 + col) * 256 + quad * 8;
    const unsigned short* ar1 = ar0 + 16 * 256;
    const unsigned short* br  = WT + (size_t)(head * 64 + col) * 256 + quad * 8;

    f4 C[2][4];
    #pragma unroll
    for (int a = 0; a < 2; a++)
        #pragma unroll
        for (int b = 0; b < 4; b++) C[a][b] = f4{0.f, 0.f, 0.f, 0.f};

    #pragma unroll
    for (int kk = 0; kk < 256; kk += 32) {
        short8 a0 = *(const short8*)(ar0 + kk);
        short8 a1 = *(const short8*)(ar1 + kk);
        #pragma unroll
        for (int nt = 0; nt < 4; nt++) {
            short8 bf = *(const short8*)(br + nt * 16 * 256 + kk);
            C[0][nt] = __builtin_amdgcn_mfma_f32_16x16x32_bf16(a0, bf, C[0][nt], 0, 0, 0);
            C[1][nt] = __builtin_amdgcn_mfma_f32_16x16x32_bf16(a1, bf, C[1][nt], 0, 0, 0);
        }
    }

    float as_[4], ad_[4];
    #pragma unroll
    for (int nt = 0; nt < 4; nt++) {
        as_[nt] = aS[head * 64 + nt * 16 + col];
        ad_[nt] = aD[head * 64 + nt * 16 + col];
    }
    #pragma unroll
    for (int mt = 0; mt < 2; mt++) {
        #pragma unroll
        for (int r = 0; r < 4; r++) {
            float sv = 0.f, dv = 0.f;
            #pragma unroll
            for (int nt = 0; nt < 4; nt++) {
                sv += C[mt][nt][r] * as_[nt];
                dv += C[mt][nt][r] * ad_[nt];
            }
            #pragma unroll
            for (int m = 1; m < 16; m <<= 1) {
                sv += __shfl_xor(sv, m, 64);
                dv += __shfl_xor(dv, m, 64);
            }
            if (col == 0) {
                int i = i0 + mt * 16 + quad * 4 + r;
                float zs = sv * 1.4426950408889634f;   // log2(e) folded
                float zd = dv * 1.4426950408889634f;
                sE [head * NN + i] = __builtin_amdgcn_exp2f(zs);
                sE2[head * NN + i] = __builtin_amdgcn_exp2f(0.2f * zs);
                dE [head * NN + i] = __builtin_amdgcn_exp2f(zd);
                dE2[head * NN + i] = __builtin_amdgcn_exp2f(0.2f * zd);
            }
        }
    }

    // hF scatter into bf16 B-fragment order
    const size_t fbase = (((size_t)blockIdx.x * HEADS + head) * 4) * 512;
    #pragma unroll
    for (int mt = 0; mt < 2; mt++) {
        #pragma unroll
        for (int nt = 0; nt < 4; nt++) {
            #pragma unroll
            for (int r = 0; r < 4; r++) {
                int il = mt * 16 + quad * 4 + r;
                int qp = il >> 3;
                int t  = il & 7;
                hF[fbase + (size_t)nt * 512 + (qp * 16 + col) * 8 + t] =
                    f2bf(C[mt][nt][r]);
            }
        }
    }
}

// ---------------- K2: fused masked softmax-weight + aggregation ----------
// Math bit-identical to round-2 (fp32 products, +0x8000 bf16 pack); masking
// via byte-mask perm+and (masked lanes -> exact 0x0000 bf16, same as before).
__device__ __forceinline__ short8 build_w(const u2& ab,
                                          const f4& alo, const f4& ahi,
                                          const f4& blo, const f4& bhi,
                                          float es, float es2) {
    f4 esv  = f4{es, es, es, es};
    f4 es2v = f4{es2, es2, es2, es2};
    f4 x0 = esv * alo,  x1 = esv * ahi;
    f4 y0 = es2v * blo, y1 = es2v * bhi;
    f4 m0 = __builtin_elementwise_max(x0, y0);
    f4 m1 = __builtin_elementwise_max(x1, y1);
    float mm[8] = {m0[0], m0[1], m0[2], m0[3], m1[0], m1[1], m1[2], m1[3]};
    u4 pv;
    #pragma unroll
    for (int k = 0; k < 4; ++k) {
        uint32 src = (k < 2) ? ab.x : ab.y;
        uint32 sel = (k & 1) ? 0x07070606u : 0x05050404u;   // replicate mask bytes
        uint32 mkw = __builtin_amdgcn_perm(src, 0u, sel);   // {m0 m0 m1 m1} bytes
        uint32 e0 = __builtin_bit_cast(uint32, mm[2 * k])     + 0x8000u;
        uint32 e1 = __builtin_bit_cast(uint32, mm[2 * k + 1]) + 0x8000u;
        uint32 packed = __builtin_amdgcn_perm(e1, e0, 0x07060302u); // bf16 pair
        pv[k] = packed & mkw;
    }
    return __builtin_bit_cast(short8, pv);
}

// grid = 256 i-tiles * jsplit; block = 256 thr (wave = head).
__global__ __launch_bounds__(256, 4) void k2_gat(
    const unsigned char* __restrict__ adjF, const unsigned short* __restrict__ hF,
    const float* __restrict__ sE, const float* __restrict__ sE2,
    const float* __restrict__ dE, const float* __restrict__ dE2,
    float* __restrict__ Pout, float* __restrict__ PS, int jchunk)
{
    const int tid   = threadIdx.x;
    const int head  = tid >> 6;
    const int lane  = tid & 63;
    const int col   = lane & 15;
    const int quad  = lane >> 4;
    const int itile = blockIdx.x & 255;
    const int split = blockIdx.x >> 8;
    const int i0    = itile * 32;
    const int j0    = split * jchunk;

    const float es0  = sE [head * NN + i0 + col];
    const float es0b = sE2[head * NN + i0 + col];
    const float es1  = sE [head * NN + i0 + 16 + col];
    const float es1b = sE2[head * NN + i0 + 16 + col];

    const unsigned char* abase =
        adjF + (size_t)(itile * 256 + (j0 >> 5)) * 1024 + lane * 8;
    const float* dEp  = dE  + head * NN + j0 + quad * 8;
    const float* dE2p = dE2 + head * NN + j0 + quad * 8;
    const unsigned short* hbase =
        hF + ((size_t)(j0 >> 5) * HEADS + head) * 4 * 512 + lane * 8;

    f4 acc[2][4];
    f4 accS[2];
    #pragma unroll
    for (int a = 0; a < 2; a++) {
        accS[a] = f4{0.f, 0.f, 0.f, 0.f};
        #pragma unroll
        for (int b = 0; b < 4; b++) acc[a][b] = f4{0.f, 0.f, 0.f, 0.f};
    }
    short8 ones;
    #pragma unroll
    for (int t = 0; t < 8; t++) ones[t] = (short)0x3F80;   // bf16 1.0

    const int ngrp = jchunk >> 5;             // 32 j per iteration
    #pragma unroll 2
    for (int g = 0; g < ngrp; ++g) {
        u2 a0 = *(const u2*)(abase + (size_t)g * 1024);
        u2 a1 = *(const u2*)(abase + (size_t)g * 1024 + 512);
        f4 alo = *(const f4*)(dEp  + g * 32);
        f4 ahi = *(const f4*)(dEp  + g * 32 + 4);
        f4 blo = *(const f4*)(dE2p + g * 32);
        f4 bhi = *(const f4*)(dE2p + g * 32 + 4);
        const unsigned short* hp = hbase + (size_t)g * (HEADS * 4 * 512);
        short8 B0 = *(const short8*)(hp);
        short8 B1 = *(const short8*)(hp + 512);
        short8 B2 = *(const short8*)(hp + 1024);
        short8 B3 = *(const short8*)(hp + 1536);

        short8 af0 = build_w(a0, alo, ahi, blo, bhi, es0, es0b);
        short8 af1 = build_w(a1, alo, ahi, blo, bhi, es1, es1b);

        acc[0][0] = __builtin_amdgcn_mfma_f32_16x16x32_bf16(af0, B0, acc[0][0], 0, 0, 0);
        acc[0][1] = __builtin_amdgcn_mfma_f32_16x16x32_bf16(af0, B1, acc[0][1], 0, 0, 0);
        acc[0][2] = __builtin_amdgcn_mfma_f32_16x16x32_bf16(af0, B2, acc[0][2], 0, 0, 0);
        acc[0][3] = __builtin_amdgcn_mfma_f32_16x16x32_bf16(af0, B3, acc[0][3], 0, 0, 0);
        accS[0]   = __builtin_amdgcn_mfma_f32_16x16x32_bf16(af0, ones, accS[0], 0, 0, 0);
        acc[1][0] = __builtin_amdgcn_mfma_f32_16x16x32_bf16(af1, B0, acc[1][0], 0, 0, 0);
        acc[1][1] = __builtin_amdgcn_mfma_f32_16x16x32_bf16(af1, B1, acc[1][1], 0, 0, 0);
        acc[1][2] = __builtin_amdgcn_mfma_f32_16x16x32_bf16(af1, B2, acc[1][2], 0, 0, 0);
        acc[1][3] = __builtin_amdgcn_mfma_f32_16x16x32_bf16(af1, B3, acc[1][3], 0, 0, 0);
        accS[1]   = __builtin_amdgcn_mfma_f32_16x16x32_bf16(af1, ones, accS[1], 0, 0, 0);
    }

    #pragma unroll
    for (int mt = 0; mt < 2; mt++) {
        #pragma unroll
        for (int nt = 0; nt < 4; nt++) {
            #pragma unroll
            for (int r = 0; r < 4; r++) {
                int row = i0 + mt * 16 + quad * 4 + r;
                Pout[((size_t)split * NN + row) * 256 + head * 64 + nt * 16 + col] =
                    acc[mt][nt][r];
            }
        }
        if (col == 0) {
            #pragma unroll
            for (int r = 0; r < 4; r++) {
                int row = i0 + mt * 16 + quad * 4 + r;
                PS[((size_t)split * NN + row) * HEADS + head] = accS[mt][r];
            }
        }
    }
}

// ---------------- K3: reduce splits, normalize, add bias ------------------
__global__ void k3_norm(const float* __restrict__ Pout, const float* __restrict__ PS,
                        const float* __restrict__ bias, float* __restrict__ out,
                        int jsplit)
{
    int t  = blockIdx.x * 256 + threadIdx.x;
    int c4 = t * 4;
    int i    = c4 >> 8;
    int cb   = c4 & 255;
    int head = cb >> 6;
    f4 num = f4{0.f, 0.f, 0.f, 0.f};
    float den = 0.f;
    for (int s = 0; s < jsplit; s++) {
        num += *(const f4*)(Pout + ((size_t)s * NN + i) * 256 + cb);
        den += PS[((size_t)s * NN + i) * HEADS + head];
    }
    f4 bv = *(const f4*)(bias + cb);
    f4 o  = num * (1.0f / den) + bv;
    *(f4*)(out + c4) = o;
}

extern "C" void kernel_launch(void* const* d_in, const int* in_sizes, int n_in,
                              void* d_out, int out_size, void* d_ws, size_t ws_size,
                              hipStream_t stream) {
    (void)in_sizes; (void)n_in; (void)out_size;
    const float* x    = (const float*)d_in[0];
    const int*   adj  = (const int*)d_in[1];
    const float* W    = (const float*)d_in[2];
    const float* aS   = (const float*)d_in[3];
    const float* aD   = (const float*)d_in[4];
    const float* bias = (const float*)d_in[5];
    float* out = (float*)d_out;

    char* ws = (char*)d_ws;
    unsigned short* xb = (unsigned short*)(ws);              //  4 MB
    unsigned short* WT = (unsigned short*)(ws +  4194304);   //  128 KB
    unsigned short* hF = (unsigned short*)(ws +  4325376);   //  4 MB
    float*  sE   = (float*)(ws +  8519680);                  //  128 KB
    float*  sE2  = (float*)(ws +  8650752);                  //  128 KB
    float*  dE   = (float*)(ws +  8781824);                  //  128 KB
    float*  dE2  = (float*)(ws +  8912896);                  //  128 KB
    unsigned char* adjF = (unsigned char*)(ws + 9043968);    //  64 MB
    float*  PS   = (float*)(ws + 76152832);                  //  up to 1 MB
    float*  Pout = (float*)(ws + 77201408);                  //  jsplit * 8 MB

    const size_t need8 = 77201408ull + 8ull * 8388608ull;
    const int jsplit = (ws_size >= need8) ? 8 : 4;
    const int jchunk = NN / jsplit;

    k0_convert<<<2304, 256, 0, stream>>>(x, W, xb, WT);
    kpack<<<8192, 256, 0, stream>>>(adj, adjF);
    k1_hgemm<<<256, 256, 0, stream>>>(xb, WT, aS, aD, hF, sE, sE2, dE, dE2);
    k2_gat<<<256 * jsplit, 256, 0, stream>>>(adjF, hF, sE, sE2, dE, dE2, Pout, PS, jchunk);
    k3_norm<<<2048, 256, 0, stream>>>(Pout, PS, bias, out, jsplit);
}